// Round 7
// baseline (211.406 us; speedup 1.0000x reference)
//
#include <hip/hip_runtime.h>

#define D 4096
#define DM 4095
#define BS 128   // bundle size
#define NROW 64  // B * nb = 4 * 16

#define ZSTR 520  // u16 stride of zsh rows (65 groups, ==1 mod 8 -> conflict-free)
#define PSTR 616  // u16 stride of parity rows (77 groups, ==5 mod 8)

typedef __attribute__((ext_vector_type(8))) short bf16x8;
typedef __attribute__((ext_vector_type(4))) float f32x4;

// round-to-nearest-even f32 -> bf16 bits
__device__ __forceinline__ unsigned short f2bf(float f) {
  union { float f; unsigned int u; } v;
  v.f = f;
  const unsigned int r = v.u + 0x7fffu + ((v.u >> 16) & 1u);
  return (unsigned short)(r >> 16);
}

// ---------- kernel 1: fused softmax + shifted weighted sum -> bf16 z --------
// z[row][m] = sum_{s=0..127} softmax(pw)[s] * tok[row][s][(m+s)%D]
// Block = (m-chunk of 512, row). Thread t: output group og; s-half h = t>>7.
__global__ __launch_bounds__(256) void zshift_k(const float* __restrict__ tok,
                                                const float* __restrict__ pw,
                                                unsigned short* __restrict__ zb) {
  const int t = threadIdx.x;
  const int mc = blockIdx.x;   // 0..7
  const int row = blockIdx.y;  // 0..63

  __shared__ float wsh[BS];
  __shared__ float red[4];
  __shared__ float4 xsh[128];
  {
    const float v = (t < BS) ? pw[t] : -1e30f;
    float m = v;
#pragma unroll
    for (int o = 32; o > 0; o >>= 1) m = fmaxf(m, __shfl_xor(m, o));
    if ((t & 63) == 0) red[t >> 6] = m;
    __syncthreads();
    m = fmaxf(fmaxf(red[0], red[1]), fmaxf(red[2], red[3]));
    const float e = (t < BS) ? expf(v - m) : 0.f;
    float s = e;
#pragma unroll
    for (int o = 32; o > 0; o >>= 1) s += __shfl_xor(s, o);
    __syncthreads();
    if ((t & 63) == 0) red[t >> 6] = s;
    __syncthreads();
    s = red[0] + red[1] + red[2] + red[3];
    if (t < BS) wsh[t] = e / s;
    __syncthreads();
  }

  const int g = t & 127;        // local output group
  const int h = t >> 7;         // s-half (wave-uniform)
  const int og = (mc << 7) + g; // global output group (4 floats)
  const float4* tr = (const float4*)(tok + (size_t)row * (BS * D));

  float4 acc = make_float4(0.f, 0.f, 0.f, 0.f);
#pragma unroll
  for (int qq = 0; qq < 16; ++qq) {
    const int q = (h << 4) + qq;   // s-quad, s = 4q + r
    const float w0 = wsh[4 * q + 0], w1 = wsh[4 * q + 1];
    const float w2 = wsh[4 * q + 2], w3 = wsh[4 * q + 3];
    const int G = (og + q) & 1023;
    const int G1 = (G + 1) & 1023;
    const size_t r0 = (size_t)(4 * q + 0) << 10;
    const size_t r1 = (size_t)(4 * q + 1) << 10;
    const size_t r2 = (size_t)(4 * q + 2) << 10;
    const size_t r3 = (size_t)(4 * q + 3) << 10;
    const float4 a0 = tr[r0 + G];
    const float4 a1 = tr[r1 + G], b1 = tr[r1 + G1];
    const float4 a2 = tr[r2 + G], b2 = tr[r2 + G1];
    const float4 a3 = tr[r3 + G], b3 = tr[r3 + G1];
    acc.x += w0 * a0.x; acc.y += w0 * a0.y;
    acc.z += w0 * a0.z; acc.w += w0 * a0.w;
    acc.x += w1 * a1.y; acc.y += w1 * a1.z;
    acc.z += w1 * a1.w; acc.w += w1 * b1.x;
    acc.x += w2 * a2.z; acc.y += w2 * a2.w;
    acc.z += w2 * b2.x; acc.w += w2 * b2.y;
    acc.x += w3 * a3.w; acc.y += w3 * b3.x;
    acc.z += w3 * b3.y; acc.w += w3 * b3.z;
  }
  if (h) xsh[g] = acc;
  __syncthreads();
  if (!h) {
    const float4 o = xsh[g];
    ushort4 u;
    u.x = f2bf(acc.x + o.x);
    u.y = f2bf(acc.y + o.y);
    u.z = f2bf(acc.z + o.z);
    u.w = f2bf(acc.w + o.w);
    *(ushort4*)(zb + (size_t)row * D + ((size_t)og << 2)) = u;
  }
}

// ---------- kernel 2: full-K circulant matmul via bf16 MFMA -----------------
// bundle[row][d] = sum_{m=0..4095} z[row][m] * base[(m-d)%D]
// C^T formulation: M=d (A = circulant), N=row (B = z), K=m.
// Grid (dg 0..63, rt 0..3); block owns a 16-row x 64-d tile, loops K in 8
// chunks of 512 with double-buffered LDS staging.
__global__ __launch_bounds__(256) void corr_k(const unsigned short* __restrict__ zb,
                                              const float* __restrict__ base,
                                              float* __restrict__ bundle) {
  __shared__ __align__(16) unsigned short zsh[2][16 * ZSTR];
  __shared__ __align__(16) unsigned short psh[2][8 * PSTR];
  const int t = threadIdx.x;
  const int dg = blockIdx.x;   // 0..63
  const int rt = blockIdx.y;   // 0..3
  const int d0b = dg << 6;

  const int rr = t >> 4;             // z-stage: row 0..15
  const int c0 = (t & 15) << 5;      // z-stage: 32 u16 at this col
  const uint4* zsrc0 =
      (const uint4*)(zb + (size_t)(rt * 16 + rr) * D + c0);

#define STAGE(jc, b)                                                        \
  {                                                                         \
    const int jb_ = (jc) << 9;                                              \
    const uint4* src_ = zsrc0 + (jb_ >> 3);                                 \
    uint4* dst_ = (uint4*)(zsh[b] + rr * ZSTR + c0);                        \
    dst_[0] = src_[0]; dst_[1] = src_[1];                                   \
    dst_[2] = src_[2]; dst_[3] = src_[3];                                   \
    const int c0p_ = jb_ - d0b - 64 + 2 * D;                                \
    for (int idx = t; idx < 8 * PSTR; idx += 256) {                         \
      const int r_ = idx / PSTR;                                           \
      const int x_ = idx - r_ * PSTR;                                      \
      psh[b][idx] = f2bf(base[(c0p_ + r_ + x_) & DM]);                      \
    }                                                                       \
  }

  STAGE(0, 0);

  const int lane = t & 63;
  const int w = t >> 6;        // wave id: d-subtile
  const int dd = lane & 15;    // A: m-index (d offset); B: n-index (row offset)
  const int q = lane >> 4;     // k = 8q + j
  // A fragment window start: a0 = 64 + 8q - 16w - dd (in [1,88]), +32 per ks
  const int a0 = 64 + (q << 3) - (w << 4) - dd;
  const int pr = a0 & 7;
  const int px = a0 - pr;      // multiple of 8 -> 16B aligned
  const int aoff = pr * PSTR + px;
  const int boff = dd * ZSTR + (q << 3);

  f32x4 acc = {0.f, 0.f, 0.f, 0.f};
#pragma unroll 1
  for (int jc = 0; jc < 8; ++jc) {
    __syncthreads();
    if (jc < 7) STAGE(jc + 1, (jc + 1) & 1);
    const unsigned short* pA = psh[jc & 1] + aoff;
    const unsigned short* pB = zsh[jc & 1] + boff;
#pragma unroll
    for (int ks = 0; ks < 16; ++ks) {
      const bf16x8 af = *(const bf16x8*)(pA + (ks << 5));
      const bf16x8 bf = *(const bf16x8*)(pB + (ks << 5));
      acc = __builtin_amdgcn_mfma_f32_16x16x32_bf16(af, bf, acc, 0, 0, 0);
    }
  }
#undef STAGE
  // D: col(n)=lane&15 -> output row; row(m)=quad*4+reg -> d index
  const int row = rt * 16 + dd;
  const int d = d0b + (w << 4) + (q << 2);
  float4 o = make_float4(acc[0], acc[1], acc[2], acc[3]);
  *(float4*)(bundle + (size_t)row * D + d) = o;
}

// ---------- kernel 3: L2 normalize ------------------------------------------
__global__ __launch_bounds__(1024) void norm_k(const float* __restrict__ bundle,
                                               float* __restrict__ out) {
  const int t = threadIdx.x;
  const int row = blockIdx.x;
  const float4 s = ((const float4*)bundle)[(size_t)row * (D / 4) + t];
  float ssq = s.x * s.x + s.y * s.y + s.z * s.z + s.w * s.w;
#pragma unroll
  for (int o = 32; o > 0; o >>= 1) ssq += __shfl_xor(ssq, o);
  __shared__ float red[16];
  if ((t & 63) == 0) red[t >> 6] = ssq;
  __syncthreads();
  float tot = 0.f;
#pragma unroll
  for (int i = 0; i < 16; ++i) tot += red[i];
  const float sc = rsqrtf(fmaxf(tot, 1e-8f));
  float4 o;
  o.x = s.x * sc; o.y = s.y * sc; o.z = s.z * sc; o.w = s.w * sc;
  ((float4*)out)[(size_t)row * (D / 4) + t] = o;
}

extern "C" void kernel_launch(void* const* d_in, const int* in_sizes, int n_in,
                              void* d_out, int out_size, void* d_ws, size_t ws_size,
                              hipStream_t stream) {
  (void)in_sizes; (void)n_in; (void)out_size; (void)ws_size;
  const float* tok = (const float*)d_in[0];   // [4,2048,4096] f32
  const float* base = (const float*)d_in[1];  // [4096] f32
  const float* pw = (const float*)d_in[2];    // [128] f32
  float* out = (float*)d_out;                 // [64,4096] f32

  unsigned short* zb = (unsigned short*)d_ws;          // 64*4096 bf16 (512 KB)
  float* bundle = (float*)(zb + (size_t)NROW * D);     // 64*4096 f32 (1 MB)

  zshift_k<<<dim3(8, NROW), 256, 0, stream>>>(tok, pw, zb);
  corr_k<<<dim3(64, 4), 256, 0, stream>>>(zb, base, bundle);
  norm_k<<<NROW, 1024, 0, stream>>>(bundle, out);
}

// Round 8
// 205.728 us; speedup vs baseline: 1.0276x; 1.0276x over previous
//
#include <hip/hip_runtime.h>

#define D 4096
#define DM 4095
#define BS 128   // bundle size
#define NROW 64  // B * nb = 4 * 16
#define JC 8     // corr K-chunks (512 m each)

#define ZSTR 520   // u16 stride of zsh rows (65 groups, ==1 mod 8 -> conflict-free)
#define PSTR 616   // u16 stride of parity rows (77 groups, ==5 mod 8)
#define PBLEN 4736 // bf16 base ring length (>= 4095 + PSTR + 1)

typedef __attribute__((ext_vector_type(8))) short bf16x8;
typedef __attribute__((ext_vector_type(4))) float f32x4;

// round-to-nearest-even f32 -> bf16 bits
__device__ __forceinline__ unsigned short f2bf(float f) {
  union { float f; unsigned int u; } v;
  v.f = f;
  const unsigned int r = v.u + 0x7fffu + ((v.u >> 16) & 1u);
  return (unsigned short)(r >> 16);
}

// ---------- kernel 1: fused softmax + shifted weighted sum -> bf16 z --------
// z[row][m] = sum_{s=0..127} softmax(pw)[s] * tok[row][s][(m+s)%D]
// Block (0,0) additionally materializes pbase[y] = bf16(base[y & DM]).
__global__ __launch_bounds__(256) void zshift_k(const float* __restrict__ tok,
                                                const float* __restrict__ pw,
                                                const float* __restrict__ base,
                                                unsigned short* __restrict__ zb,
                                                unsigned short* __restrict__ pb) {
  const int t = threadIdx.x;
  const int mc = blockIdx.x;   // 0..7
  const int row = blockIdx.y;  // 0..63

  if (mc == 0 && row == 0) {
    for (int x = t; x < PBLEN; x += 256) pb[x] = f2bf(base[x & DM]);
  }

  __shared__ float wsh[BS];
  __shared__ float red[4];
  __shared__ float4 xsh[128];
  {
    const float v = (t < BS) ? pw[t] : -1e30f;
    float m = v;
#pragma unroll
    for (int o = 32; o > 0; o >>= 1) m = fmaxf(m, __shfl_xor(m, o));
    if ((t & 63) == 0) red[t >> 6] = m;
    __syncthreads();
    m = fmaxf(fmaxf(red[0], red[1]), fmaxf(red[2], red[3]));
    const float e = (t < BS) ? expf(v - m) : 0.f;
    float s = e;
#pragma unroll
    for (int o = 32; o > 0; o >>= 1) s += __shfl_xor(s, o);
    __syncthreads();
    if ((t & 63) == 0) red[t >> 6] = s;
    __syncthreads();
    s = red[0] + red[1] + red[2] + red[3];
    if (t < BS) wsh[t] = e / s;
    __syncthreads();
  }

  const int g = t & 127;        // local output group
  const int h = t >> 7;         // s-half (wave-uniform)
  const int og = (mc << 7) + g; // global output group (4 floats)
  const float4* tr = (const float4*)(tok + (size_t)row * (BS * D));

  float4 acc = make_float4(0.f, 0.f, 0.f, 0.f);
#pragma unroll
  for (int qq = 0; qq < 16; ++qq) {
    const int q = (h << 4) + qq;   // s-quad, s = 4q + r
    const float w0 = wsh[4 * q + 0], w1 = wsh[4 * q + 1];
    const float w2 = wsh[4 * q + 2], w3 = wsh[4 * q + 3];
    const int G = (og + q) & 1023;
    const int G1 = (G + 1) & 1023;
    const size_t r0 = (size_t)(4 * q + 0) << 10;
    const size_t r1 = (size_t)(4 * q + 1) << 10;
    const size_t r2 = (size_t)(4 * q + 2) << 10;
    const size_t r3 = (size_t)(4 * q + 3) << 10;
    const float4 a0 = tr[r0 + G];
    const float4 a1 = tr[r1 + G], b1 = tr[r1 + G1];
    const float4 a2 = tr[r2 + G], b2 = tr[r2 + G1];
    const float4 a3 = tr[r3 + G], b3 = tr[r3 + G1];
    acc.x += w0 * a0.x; acc.y += w0 * a0.y;
    acc.z += w0 * a0.z; acc.w += w0 * a0.w;
    acc.x += w1 * a1.y; acc.y += w1 * a1.z;
    acc.z += w1 * a1.w; acc.w += w1 * b1.x;
    acc.x += w2 * a2.z; acc.y += w2 * a2.w;
    acc.z += w2 * b2.x; acc.w += w2 * b2.y;
    acc.x += w3 * a3.w; acc.y += w3 * b3.x;
    acc.z += w3 * b3.y; acc.w += w3 * b3.z;
  }
  if (h) xsh[g] = acc;
  __syncthreads();
  if (!h) {
    const float4 o = xsh[g];
    ushort4 u;
    u.x = f2bf(acc.x + o.x);
    u.y = f2bf(acc.y + o.y);
    u.z = f2bf(acc.z + o.z);
    u.w = f2bf(acc.w + o.w);
    *(ushort4*)(zb + (size_t)row * D + ((size_t)og << 2)) = u;
  }
}

// ---------- kernel 2: circulant matmul via bf16 MFMA ------------------------
// braw[jc][row][d] = sum_{m in chunk} z[row][m] * base[(m-d)%D]
// C^T formulation: M=d (A = circulant), N=row (B = z), K=m.
__global__ __launch_bounds__(256) void corr_k(const unsigned short* __restrict__ zb,
                                              const unsigned short* __restrict__ pb,
                                              float* __restrict__ braw) {
  __shared__ __align__(16) unsigned short zsh[16 * ZSTR];  // 16 rows x 512 bf16
  __shared__ __align__(16) unsigned short psh[8 * PSTR];   // 8 parity copies
  const int t = threadIdx.x;
  const int jc = blockIdx.x;   // 0..7   K-chunk
  const int dg = blockIdx.y;   // 0..63  64 d's per block
  const int rt = blockIdx.z;   // 0..3   16 rows per block
  const int jb = jc << 9;
  const int d0b = dg << 6;

  // stage zsh: 16 rows x 512 bf16; thread (rr = t>>4) writes 32 u16 at (t&15)*32
  {
    const int rr = t >> 4;
    const int c0 = (t & 15) << 5;
    const uint4* src =
        (const uint4*)(zb + (size_t)(rt * 16 + rr) * D + jb + c0);
    uint4* dst = (uint4*)(zsh + rr * ZSTR + c0);
    dst[0] = src[0];
    dst[1] = src[1];
    dst[2] = src[2];
    dst[3] = src[3];
  }
  // stage parity copies from the precomputed bf16 ring:
  // psh[r][x] = pb[((jb - d0b - 64 + r) & DM) + x]  (contiguous per row)
  {
    const int r = t >> 5;       // 0..7
    const int x0 = t & 31;
    const int sr = (jb - d0b - 64 + 2 * D + r) & DM;
    const unsigned short* src = pb + sr;
    unsigned short* dst = psh + r * PSTR;
    for (int x = x0; x < PSTR; x += 32) dst[x] = src[x];
  }
  __syncthreads();

  const int lane = t & 63;
  const int w = t >> 6;        // wave id: d-subtile
  const int dd = lane & 15;    // A: m-index (d offset); B: n-index (row offset)
  const int q = lane >> 4;     // k = 8q + j
  // A fragment window start: a0 = 64 + 8q - 16w - dd (in [1,88]), +32 per ks
  const int a0 = 64 + (q << 3) - (w << 4) - dd;
  const int pr = a0 & 7;
  const int px = a0 - pr;      // multiple of 8 -> 16B aligned
  const unsigned short* pA = psh + pr * PSTR + px;
  const unsigned short* pB = zsh + dd * ZSTR + (q << 3);

  f32x4 acc = {0.f, 0.f, 0.f, 0.f};
#pragma unroll
  for (int ks = 0; ks < 16; ++ks) {
    const bf16x8 af = *(const bf16x8*)(pA + (ks << 5));
    const bf16x8 bf = *(const bf16x8*)(pB + (ks << 5));
    acc = __builtin_amdgcn_mfma_f32_16x16x32_bf16(af, bf, acc, 0, 0, 0);
  }
  // D: col(n)=lane&15 -> output row; row(m)=quad*4+reg -> d index
  const int row = rt * 16 + dd;
  const int d = d0b + (w << 4) + (q << 2);
  float4 o = make_float4(acc[0], acc[1], acc[2], acc[3]);
  *(float4*)(braw + (size_t)(jc * NROW + row) * D + d) = o;
}

// ---------- kernel 3: sum K-chunk partials + L2 normalize -------------------
__global__ __launch_bounds__(1024) void norm_k(const float* __restrict__ braw,
                                               float* __restrict__ out) {
  const int t = threadIdx.x;
  const int row = blockIdx.x;
  const float4* b4 = (const float4*)braw;
  float4 s = make_float4(0.f, 0.f, 0.f, 0.f);
#pragma unroll
  for (int p = 0; p < JC; ++p) {
    const float4 v = b4[(size_t)(p * NROW + row) * (D / 4) + t];
    s.x += v.x; s.y += v.y; s.z += v.z; s.w += v.w;
  }
  float ssq = s.x * s.x + s.y * s.y + s.z * s.z + s.w * s.w;
#pragma unroll
  for (int o = 32; o > 0; o >>= 1) ssq += __shfl_xor(ssq, o);
  __shared__ float red[16];
  if ((t & 63) == 0) red[t >> 6] = ssq;
  __syncthreads();
  float tot = 0.f;
#pragma unroll
  for (int i = 0; i < 16; ++i) tot += red[i];
  const float sc = rsqrtf(fmaxf(tot, 1e-8f));
  float4 o;
  o.x = s.x * sc; o.y = s.y * sc; o.z = s.z * sc; o.w = s.w * sc;
  ((float4*)out)[(size_t)row * (D / 4) + t] = o;
}

extern "C" void kernel_launch(void* const* d_in, const int* in_sizes, int n_in,
                              void* d_out, int out_size, void* d_ws, size_t ws_size,
                              hipStream_t stream) {
  (void)in_sizes; (void)n_in; (void)out_size; (void)ws_size;
  const float* tok = (const float*)d_in[0];   // [4,2048,4096] f32
  const float* base = (const float*)d_in[1];  // [4096] f32
  const float* pw = (const float*)d_in[2];    // [128] f32
  float* out = (float*)d_out;                 // [64,4096] f32

  unsigned short* zb = (unsigned short*)d_ws;          // 64*4096 bf16 (512 KB)
  unsigned short* pb = zb + (size_t)NROW * D;          // PBLEN bf16 (~9.5 KB)
  float* braw = (float*)(pb + 8192);                   // JC*64*4096 f32 (8 MB)

  zshift_k<<<dim3(8, NROW), 256, 0, stream>>>(tok, pw, base, zb, pb);
  corr_k<<<dim3(JC, 64, 4), 256, 0, stream>>>(zb, pb, braw);
  norm_k<<<NROW, 1024, 0, stream>>>(braw, out);
}

// Round 9
// 205.528 us; speedup vs baseline: 1.0286x; 1.0010x over previous
//
#include <hip/hip_runtime.h>

#define D 4096
#define DM 4095
#define BS 128   // bundle size
#define NROW 64  // B * nb = 4 * 16
#define JC 8     // corr K-chunks (512 m each)

#define ZSTR 520   // u16 stride of zsh rows (65 groups, ==1 mod 8 -> conflict-free)
#define PSTR 616   // u16 stride of parity rows (77 groups, ==5 mod 8)
#define PBLEN 4736 // bf16 base ring length (>= 4095 + PSTR + 1)

typedef __attribute__((ext_vector_type(8))) short bf16x8;
typedef __attribute__((ext_vector_type(4))) float f32x4;

// round-to-nearest-even f32 -> bf16 bits
__device__ __forceinline__ unsigned short f2bf(float f) {
  union { float f; unsigned int u; } v;
  v.f = f;
  const unsigned int r = v.u + 0x7fffu + ((v.u >> 16) & 1u);
  return (unsigned short)(r >> 16);
}

__device__ __forceinline__ float bf2f(unsigned short h) {
  union { unsigned int u; float f; } v;
  v.u = (unsigned int)h << 16;
  return v.f;
}

// ---------- kernel 1: fused softmax + shifted weighted sum -> bf16 z --------
// z[row][m] = sum_{s=0..127} softmax(pw)[s] * tok[row][s][(m+s)%D]
// Block (0,0) additionally materializes pbase[y] = bf16(base[y & DM]).
__global__ __launch_bounds__(256) void zshift_k(const float* __restrict__ tok,
                                                const float* __restrict__ pw,
                                                const float* __restrict__ base,
                                                unsigned short* __restrict__ zb,
                                                unsigned short* __restrict__ pb) {
  const int t = threadIdx.x;
  const int mc = blockIdx.x;   // 0..7
  const int row = blockIdx.y;  // 0..63

  if (mc == 0 && row == 0) {
    for (int x = t; x < PBLEN; x += 256) pb[x] = f2bf(base[x & DM]);
  }

  __shared__ float wsh[BS];
  __shared__ float red[4];
  __shared__ float4 xsh[128];
  {
    const float v = (t < BS) ? pw[t] : -1e30f;
    float m = v;
#pragma unroll
    for (int o = 32; o > 0; o >>= 1) m = fmaxf(m, __shfl_xor(m, o));
    if ((t & 63) == 0) red[t >> 6] = m;
    __syncthreads();
    m = fmaxf(fmaxf(red[0], red[1]), fmaxf(red[2], red[3]));
    const float e = (t < BS) ? expf(v - m) : 0.f;
    float s = e;
#pragma unroll
    for (int o = 32; o > 0; o >>= 1) s += __shfl_xor(s, o);
    __syncthreads();
    if ((t & 63) == 0) red[t >> 6] = s;
    __syncthreads();
    s = red[0] + red[1] + red[2] + red[3];
    if (t < BS) wsh[t] = e / s;
    __syncthreads();
  }

  const int g = t & 127;        // local output group
  const int h = t >> 7;         // s-half (wave-uniform)
  const int og = (mc << 7) + g; // global output group (4 floats)
  const float4* tr = (const float4*)(tok + (size_t)row * (BS * D));

  float4 acc = make_float4(0.f, 0.f, 0.f, 0.f);
#pragma unroll
  for (int qq = 0; qq < 16; ++qq) {
    const int q = (h << 4) + qq;   // s-quad, s = 4q + r
    const float w0 = wsh[4 * q + 0], w1 = wsh[4 * q + 1];
    const float w2 = wsh[4 * q + 2], w3 = wsh[4 * q + 3];
    const int G = (og + q) & 1023;
    const int G1 = (G + 1) & 1023;
    const size_t r0 = (size_t)(4 * q + 0) << 10;
    const size_t r1 = (size_t)(4 * q + 1) << 10;
    const size_t r2 = (size_t)(4 * q + 2) << 10;
    const size_t r3 = (size_t)(4 * q + 3) << 10;
    const float4 a0 = tr[r0 + G];
    const float4 a1 = tr[r1 + G], b1 = tr[r1 + G1];
    const float4 a2 = tr[r2 + G], b2 = tr[r2 + G1];
    const float4 a3 = tr[r3 + G], b3 = tr[r3 + G1];
    acc.x += w0 * a0.x; acc.y += w0 * a0.y;
    acc.z += w0 * a0.z; acc.w += w0 * a0.w;
    acc.x += w1 * a1.y; acc.y += w1 * a1.z;
    acc.z += w1 * a1.w; acc.w += w1 * b1.x;
    acc.x += w2 * a2.z; acc.y += w2 * a2.w;
    acc.z += w2 * b2.x; acc.w += w2 * b2.y;
    acc.x += w3 * a3.w; acc.y += w3 * b3.x;
    acc.z += w3 * b3.y; acc.w += w3 * b3.z;
  }
  if (h) xsh[g] = acc;
  __syncthreads();
  if (!h) {
    const float4 o = xsh[g];
    ushort4 u;
    u.x = f2bf(acc.x + o.x);
    u.y = f2bf(acc.y + o.y);
    u.z = f2bf(acc.z + o.z);
    u.w = f2bf(acc.w + o.w);
    *(ushort4*)(zb + (size_t)row * D + ((size_t)og << 2)) = u;
  }
}

// ---------- kernel 2: circulant matmul via bf16 MFMA ------------------------
// braw[jc][row][d] = bf16( sum_{m in chunk} z[row][m] * base[(m-d)%D] )
// C^T formulation: M=d (A = circulant), N=row (B = z), K=m.
__global__ __launch_bounds__(256) void corr_k(const unsigned short* __restrict__ zb,
                                              const unsigned short* __restrict__ pb,
                                              unsigned short* __restrict__ braw) {
  __shared__ __align__(16) unsigned short zsh[16 * ZSTR];  // 16 rows x 512 bf16
  __shared__ __align__(16) unsigned short psh[8 * PSTR];   // 8 parity copies
  const int t = threadIdx.x;
  const int jc = blockIdx.x;   // 0..7   K-chunk
  const int dg = blockIdx.y;   // 0..63  64 d's per block
  const int rt = blockIdx.z;   // 0..3   16 rows per block
  const int jb = jc << 9;
  const int d0b = dg << 6;

  // stage zsh: 16 rows x 512 bf16; thread (rr = t>>4) writes 32 u16 at (t&15)*32
  {
    const int rr = t >> 4;
    const int c0 = (t & 15) << 5;
    const uint4* src =
        (const uint4*)(zb + (size_t)(rt * 16 + rr) * D + jb + c0);
    uint4* dst = (uint4*)(zsh + rr * ZSTR + c0);
    dst[0] = src[0];
    dst[1] = src[1];
    dst[2] = src[2];
    dst[3] = src[3];
  }
  // stage parity copies from the precomputed bf16 ring:
  // psh[r][x] = pb[((jb - d0b - 64 + r) & DM) + x]  (contiguous per row)
  {
    const int r = t >> 5;       // 0..7
    const int x0 = t & 31;
    const int sr = (jb - d0b - 64 + 2 * D + r) & DM;
    const unsigned short* src = pb + sr;
    unsigned short* dst = psh + r * PSTR;
    for (int x = x0; x < PSTR; x += 32) dst[x] = src[x];
  }
  __syncthreads();

  const int lane = t & 63;
  const int w = t >> 6;        // wave id: d-subtile
  const int dd = lane & 15;    // A: m-index (d offset); B: n-index (row offset)
  const int q = lane >> 4;     // k = 8q + j
  // A fragment window start: a0 = 64 + 8q - 16w - dd (in [1,88]), +32 per ks
  const int a0 = 64 + (q << 3) - (w << 4) - dd;
  const int pr = a0 & 7;
  const int px = a0 - pr;      // multiple of 8 -> 16B aligned
  const unsigned short* pA = psh + pr * PSTR + px;
  const unsigned short* pB = zsh + dd * ZSTR + (q << 3);

  f32x4 acc = {0.f, 0.f, 0.f, 0.f};
#pragma unroll
  for (int ks = 0; ks < 16; ++ks) {
    const bf16x8 af = *(const bf16x8*)(pA + (ks << 5));
    const bf16x8 bf = *(const bf16x8*)(pB + (ks << 5));
    acc = __builtin_amdgcn_mfma_f32_16x16x32_bf16(af, bf, acc, 0, 0, 0);
  }
  // D: col(n)=lane&15 -> output row; row(m)=quad*4+reg -> d index
  const int row = rt * 16 + dd;
  const int d = d0b + (w << 4) + (q << 2);
  ushort4 u;
  u.x = f2bf(acc[0]);
  u.y = f2bf(acc[1]);
  u.z = f2bf(acc[2]);
  u.w = f2bf(acc[3]);
  *(ushort4*)(braw + (size_t)(jc * NROW + row) * D + d) = u;
}

// ---------- kernel 3: sum K-chunk partials + L2 normalize -------------------
__global__ __launch_bounds__(1024) void norm_k(const unsigned short* __restrict__ braw,
                                               float* __restrict__ out) {
  const int t = threadIdx.x;
  const int row = blockIdx.x;
  float4 s = make_float4(0.f, 0.f, 0.f, 0.f);
#pragma unroll
  for (int p = 0; p < JC; ++p) {
    const ushort4 v = *(const ushort4*)(braw +
        (size_t)(p * NROW + row) * D + (t << 2));
    s.x += bf2f(v.x); s.y += bf2f(v.y); s.z += bf2f(v.z); s.w += bf2f(v.w);
  }
  float ssq = s.x * s.x + s.y * s.y + s.z * s.z + s.w * s.w;
#pragma unroll
  for (int o = 32; o > 0; o >>= 1) ssq += __shfl_xor(ssq, o);
  __shared__ float red[16];
  if ((t & 63) == 0) red[t >> 6] = ssq;
  __syncthreads();
  float tot = 0.f;
#pragma unroll
  for (int i = 0; i < 16; ++i) tot += red[i];
  const float sc = rsqrtf(fmaxf(tot, 1e-8f));
  float4 o;
  o.x = s.x * sc; o.y = s.y * sc; o.z = s.z * sc; o.w = s.w * sc;
  ((float4*)out)[(size_t)row * (D / 4) + t] = o;
}

extern "C" void kernel_launch(void* const* d_in, const int* in_sizes, int n_in,
                              void* d_out, int out_size, void* d_ws, size_t ws_size,
                              hipStream_t stream) {
  (void)in_sizes; (void)n_in; (void)out_size; (void)ws_size;
  const float* tok = (const float*)d_in[0];   // [4,2048,4096] f32
  const float* base = (const float*)d_in[1];  // [4096] f32
  const float* pw = (const float*)d_in[2];    // [128] f32
  float* out = (float*)d_out;                 // [64,4096] f32

  unsigned short* zb = (unsigned short*)d_ws;          // 64*4096 bf16 (512 KB)
  unsigned short* pb = zb + (size_t)NROW * D;          // PBLEN bf16 (~9.5 KB)
  unsigned short* braw = pb + 8192;                    // JC*64*4096 bf16 (4 MB)

  zshift_k<<<dim3(8, NROW), 256, 0, stream>>>(tok, pw, base, zb, pb);
  corr_k<<<dim3(JC, 64, 4), 256, 0, stream>>>(zb, pb, braw);
  norm_k<<<NROW, 1024, 0, stream>>>(braw, out);
}